// Round 4
// baseline (117.823 us; speedup 1.0000x reference)
//
#include <hip/hip_runtime.h>

typedef __attribute__((ext_vector_type(8))) short short8;
typedef __attribute__((ext_vector_type(4))) float float4_t;

#define NB 32
#define NL 256
#define ND 128
#define OUT_PLANE (NB * ND * NL)   // elements per stacked output plane
#define XS 136                     // LDS row stride (bf16 units): conflict-free
#define FR_WORD 49152              // word-frag offset in ws (bf16 units)
#define CHRB 98304                 // bf16 chr_table offset in ws (bf16 units)

__device__ inline unsigned short f2bf(float f) {
    union { float f; unsigned int i; } c;
    c.f = f;
    unsigned int r = c.i + 0x7FFFu + ((c.i >> 16) & 1u);  // RN-even
    return (unsigned short)(r >> 16);
}

// ---------------------------------------------------------------------------
// ws prep: [0..49151] char B-frags, [49152..98303] word B-frags,
// [98304..114687] chr_table converted to bf16 (row 0 stays all-zero).
// Frag order: frag[s][nt][lane][j]; B[k'][n]: n=lane&15, k'=s*32+(lane>>4)*8+j,
// tap t=s>>2, k=(s&3)*32+(lane>>4)*8+j.  Value = W[dout][k][t].
// ---------------------------------------------------------------------------
__global__ void make_frags(const float* __restrict__ Wc,
                           const float* __restrict__ Ww,
                           const float* __restrict__ chrT,
                           unsigned short* __restrict__ out) {
    int i = blockIdx.x * 256 + threadIdx.x;            // 0..114687
    if (i < CHRB) {
        const float* W = (i < FR_WORD) ? Wc : Ww;
        int ii = (i < FR_WORD) ? i : i - FR_WORD;
        int j    = ii & 7;
        int lane = (ii >> 3) & 63;
        int nt   = (ii >> 9) & 7;
        int s    = ii >> 12;
        int dout = nt * 16 + (lane & 15);
        int t    = s >> 2;
        int k    = (s & 3) * 32 + ((lane >> 4) & 3) * 8 + j;
        out[i] = f2bf(W[(dout * 128 + k) * 3 + t]);
    } else {
        int j = i - CHRB;                              // 0..16383
        out[i] = f2bf(chrT[j]);
    }
}

// ---------------------------------------------------------------------------
// Merged conv kernel. Blocks 0..511: word path (LDS-staged, 16 l each).
// Blocks 512..1535: char path (8 words/block, direct A-fragment gather from
// the L1-resident bf16 chr_table — no LDS, no barriers).
// Block = 128 thr = 2 waves; wave w covers douts [w*64, w*64+64).
// ---------------------------------------------------------------------------
__global__ __launch_bounds__(128, 2) void conv_kernel(
    const int* __restrict__ wv, const int* __restrict__ wic,
    const float* __restrict__ wordT,
    const unsigned short* __restrict__ ws,
    const float* __restrict__ biasC, const float* __restrict__ biasW,
    float* __restrict__ out) {
    __shared__ unsigned short X[18 * XS];
    const int tid  = threadIdx.x;
    const int wave = tid >> 6, lane = tid & 63;
    const int m = lane & 15, quad = lane >> 4;
    const int bid = blockIdx.x;

    if (bid >= 512) {
        // ------------------------- char path -------------------------------
        const unsigned short* chrB = ws + CHRB;
        const int w0 = (bid - 512) * 8;
        short8 bfrag[12][4];
#pragma unroll
        for (int s = 0; s < 12; ++s)
#pragma unroll
            for (int p = 0; p < 4; ++p)
                bfrag[s][p] = *(const short8*)(
                    ws + (((s * 8 + wave * 4 + p) * 64 + lane) << 3));
        float bb[4];
#pragma unroll
        for (int p = 0; p < 4; ++p) bb[p] = biasC[wave * 64 + p * 16 + m];

        // idx prefetch for word 0: rows m-1, m, m+1 (OOB -> row 0 = zeros)
        int base = w0 * 16 + m;
        int i0 = (m >= 1)  ? wic[base - 1] : 0;
        int i1 = wic[base];
        int i2 = (m < 15) ? wic[base + 1] : 0;

#pragma unroll
        for (int wl = 0; wl < 8; ++wl) {
            const int w = w0 + wl;
            const unsigned short* r0 = chrB + i0 * 128 + (quad << 3);
            const unsigned short* r1 = chrB + i1 * 128 + (quad << 3);
            const unsigned short* r2 = chrB + i2 * 128 + (quad << 3);
            // A-frag source per k-step s: row (s>>2), chunk (s&3)*32 shorts
            short8 A[4];
            A[0] = *(const short8*)(r0);
            A[1] = *(const short8*)(r0 + 32);
            A[2] = *(const short8*)(r0 + 64);
            A[3] = *(const short8*)(r0 + 96);

            if (wl < 7) {  // prefetch next word's idx under the MFMAs
                int nb = (w + 1) * 16 + m;
                i0 = (m >= 1)  ? wic[nb - 1] : 0;
                i1 = wic[nb];
                i2 = (m < 15) ? wic[nb + 1] : 0;
            }

            float4_t acc[4];
#pragma unroll
            for (int p = 0; p < 4; ++p) acc[p] = (float4_t){0.f, 0.f, 0.f, 0.f};

#pragma unroll
            for (int s = 0; s < 4; ++s) {   // phase 1: s=0..3, load s+4
                short8 a = A[s];
                A[s] = *(const short8*)(r1 + (s << 5));
#pragma unroll
                for (int p = 0; p < 4; ++p)
                    acc[p] = __builtin_amdgcn_mfma_f32_16x16x32_bf16(
                        a, bfrag[s][p], acc[p], 0, 0, 0);
            }
#pragma unroll
            for (int s = 0; s < 4; ++s) {   // phase 2: s=4..7, load s+8
                short8 a = A[s];
                A[s] = *(const short8*)(r2 + (s << 5));
#pragma unroll
                for (int p = 0; p < 4; ++p)
                    acc[p] = __builtin_amdgcn_mfma_f32_16x16x32_bf16(
                        a, bfrag[s + 4][p], acc[p], 0, 0, 0);
            }
#pragma unroll
            for (int s = 0; s < 4; ++s) {   // phase 3: s=8..11
#pragma unroll
                for (int p = 0; p < 4; ++p)
                    acc[p] = __builtin_amdgcn_mfma_f32_16x16x32_bf16(
                        A[s], bfrag[s + 8][p], acc[p], 0, 0, 0);
            }

            // epilogue: max over 16 c-rows, +bias, store out1[b][dout][l]
            int b = w >> 8, l = w & 255;
            float* obase = out + OUT_PLANE + b * (ND * NL) + l;
#pragma unroll
            for (int p = 0; p < 4; ++p) {
                float v = fmaxf(fmaxf(acc[p].x, acc[p].y),
                                fmaxf(acc[p].z, acc[p].w));
                v = fmaxf(v, __shfl_xor(v, 16, 64));
                v = fmaxf(v, __shfl_xor(v, 32, 64));
                v += bb[p];
                if (quad == 0) obase[(wave * 64 + p * 16 + m) * NL] = v;
            }
        }
    } else {
        // ------------------------- word path -------------------------------
        const int b = bid >> 4, l0 = (bid & 15) << 4;
        short8 bfrag[12][4];
#pragma unroll
        for (int s = 0; s < 12; ++s)
#pragma unroll
            for (int p = 0; p < 4; ++p)
                bfrag[s][p] = *(const short8*)(
                    ws + FR_WORD + (((s * 8 + wave * 4 + p) * 64 + lane) << 3));
        float bb[4];
#pragma unroll
        for (int p = 0; p < 4; ++p) bb[p] = biasW[wave * 64 + p * 16 + m];

#pragma unroll
        for (int i0 = 0; i0 < 2; ++i0) {   // 18 rows x 8 segs = 144 jobs
            int i = tid + i0 * 128;
            if (i < 144) {
                int rr = i >> 3, sg = i & 7;
                int l = l0 + rr - 1;
                int idx = (l >= 0 && l < NL) ? wv[b * NL + l] : 0;  // row0=zeros
                const float4_t* src =
                    (const float4_t*)(wordT + idx * 128 + sg * 16);
                float4_t f0 = src[0], f1 = src[1], f2 = src[2], f3 = src[3];
                unsigned short t16[16];
                t16[0]=f2bf(f0.x); t16[1]=f2bf(f0.y); t16[2]=f2bf(f0.z); t16[3]=f2bf(f0.w);
                t16[4]=f2bf(f1.x); t16[5]=f2bf(f1.y); t16[6]=f2bf(f1.z); t16[7]=f2bf(f1.w);
                t16[8]=f2bf(f2.x); t16[9]=f2bf(f2.y); t16[10]=f2bf(f2.z); t16[11]=f2bf(f2.w);
                t16[12]=f2bf(f3.x); t16[13]=f2bf(f3.y); t16[14]=f2bf(f3.z); t16[15]=f2bf(f3.w);
                *(short8*)&X[rr * XS + sg * 16]     = *(const short8*)&t16[0];
                *(short8*)&X[rr * XS + sg * 16 + 8] = *(const short8*)&t16[8];
            }
        }
        __syncthreads();

        float4_t acc[4];
#pragma unroll
        for (int p = 0; p < 4; ++p) acc[p] = (float4_t){0.f, 0.f, 0.f, 0.f};
#pragma unroll
        for (int s = 0; s < 12; ++s) {
            short8 a = *(const short8*)&X[(m + (s >> 2)) * XS +
                                          (s & 3) * 32 + quad * 8];
#pragma unroll
            for (int p = 0; p < 4; ++p)
                acc[p] = __builtin_amdgcn_mfma_f32_16x16x32_bf16(
                    a, bfrag[s][p], acc[p], 0, 0, 0);
        }

        // D[row = l_local = quad*4+reg][col = dout_local = m]; 4 l's per lane
        float* obase = out + b * (ND * NL) + l0 + quad * 4;
#pragma unroll
        for (int p = 0; p < 4; ++p) {
            int dout = wave * 64 + p * 16 + m;
            float4_t pk;
            pk.x = acc[p].x + bb[p];
            pk.y = acc[p].y + bb[p];
            pk.z = acc[p].z + bb[p];
            pk.w = acc[p].w + bb[p];
            *(float4_t*)&obase[dout * NL] = pk;
        }
    }
}

extern "C" void kernel_launch(void* const* d_in, const int* in_sizes, int n_in,
                              void* d_out, int out_size, void* d_ws,
                              size_t ws_size, hipStream_t stream) {
    const int* word_vector   = (const int*)d_in[0];
    const int* words_in_char = (const int*)d_in[1];
    const float* word_table  = (const float*)d_in[2];
    const float* chr_table   = (const float*)d_in[3];
    const float* conv_chr_w  = (const float*)d_in[4];
    const float* conv_chr_b  = (const float*)d_in[5];
    const float* conv_word_w = (const float*)d_in[6];
    const float* conv_word_b = (const float*)d_in[7];
    float* out            = (float*)d_out;
    unsigned short* wsp   = (unsigned short*)d_ws;  // frags + bf16 chr_table

    make_frags<<<448, 256, 0, stream>>>(conv_chr_w, conv_word_w, chr_table, wsp);
    conv_kernel<<<1536, 128, 0, stream>>>(word_vector, words_in_char,
                                          word_table, wsp,
                                          conv_chr_b, conv_word_b, out);
}

// Round 5
// 107.621 us; speedup vs baseline: 1.0948x; 1.0948x over previous
//
#include <hip/hip_runtime.h>

typedef __attribute__((ext_vector_type(8))) short short8;
typedef __attribute__((ext_vector_type(4))) float float4_t;

#define NB 32
#define NL 256
#define ND 128
#define OUT_PLANE (NB * ND * NL)   // elements per stacked output plane
#define XS 136                     // LDS row stride (bf16 units): conflict-free
#define FR_WORD 49152              // word-frag offset in ws (bf16 units)
#define CHRB 98304                 // bf16 chr_table offset in ws (bf16 units)

__device__ inline unsigned short f2bf(float f) {
    union { float f; unsigned int i; } c;
    c.f = f;
    unsigned int r = c.i + 0x7FFFu + ((c.i >> 16) & 1u);  // RN-even
    return (unsigned short)(r >> 16);
}

// ---------------------------------------------------------------------------
// ws prep: [0..49151] char B-frags, [49152..98303] word B-frags,
// [98304..114687] chr_table converted to bf16 (row 0 stays all-zero).
// Frag order: frag[s][nt][lane][j]; B[k'][n]: n=lane&15, k'=s*32+(lane>>4)*8+j,
// tap t=s>>2, k=(s&3)*32+(lane>>4)*8+j.  Value = W[dout][k][t].
// ---------------------------------------------------------------------------
__global__ void make_frags(const float* __restrict__ Wc,
                           const float* __restrict__ Ww,
                           const float* __restrict__ chrT,
                           unsigned short* __restrict__ out) {
    int i = blockIdx.x * 256 + threadIdx.x;            // 0..114687
    if (i < CHRB) {
        const float* W = (i < FR_WORD) ? Wc : Ww;
        int ii = (i < FR_WORD) ? i : i - FR_WORD;
        int j    = ii & 7;
        int lane = (ii >> 3) & 63;
        int nt   = (ii >> 9) & 7;
        int s    = ii >> 12;
        int dout = nt * 16 + (lane & 15);
        int t    = s >> 2;
        int k    = (s & 3) * 32 + ((lane >> 4) & 3) * 8 + j;
        out[i] = f2bf(W[(dout * 128 + k) * 3 + t]);
    } else {
        int j = i - CHRB;                              // 0..16383
        out[i] = f2bf(chrT[j]);
    }
}

// ---------------------------------------------------------------------------
// Merged conv kernel. Blocks 0..511: word path (LDS-staged fp32->bf16, 16 l).
// Blocks 512..1535: char path: 8 words/block, double-buffered LDS staging
// from the L1-resident bf16 chr_table (no cvt VALU), one barrier per word,
// batched float4 output stores every 4 words.
// Block = 128 thr = 2 waves; wave w covers douts [w*64, w*64+64).
// ---------------------------------------------------------------------------
__global__ __launch_bounds__(128, 2) void conv_kernel(
    const int* __restrict__ wv, const int* __restrict__ wic,
    const float* __restrict__ wordT,
    const unsigned short* __restrict__ ws,
    const float* __restrict__ biasC, const float* __restrict__ biasW,
    float* __restrict__ out) {
    __shared__ unsigned short X[2][18 * XS];
    const int tid  = threadIdx.x;
    const int wave = tid >> 6, lane = tid & 63;
    const int m = lane & 15, quad = lane >> 4;
    const int bid = blockIdx.x;

    if (bid >= 512) {
        // ------------------------- char path -------------------------------
        const unsigned short* chrB = ws + CHRB;
        const int w0 = (bid - 512) * 8;        // 8 consecutive words, same b
        const int b = w0 >> 8, l0 = w0 & 255;
        short8 bfrag[12][4];
#pragma unroll
        for (int s = 0; s < 12; ++s)
#pragma unroll
            for (int p = 0; p < 4; ++p)
                bfrag[s][p] = *(const short8*)(
                    ws + (((s * 8 + wave * 4 + p) * 64 + lane) << 3));
        float bb[4];
#pragma unroll
        for (int p = 0; p < 4; ++p) bb[p] = biasC[wave * 64 + p * 16 + m];

        // zero pad rows (c=-1 and c=16) in both buffers; never overwritten
        for (int p = tid; p < XS; p += 128) {
            X[0][p] = 0; X[0][17 * XS + p] = 0;
            X[1][p] = 0; X[1][17 * XS + p] = 0;
        }
        // staging map: 256 jobs = 16 rows x 16 subs of 8 shorts (16 B);
        // thread does jobs tid (row ra) and tid+128 (row ra+8)
        const int ra = tid >> 4, sub = tid & 15;

        // prologue: stage word 0 into X[0]; prefetch idx pair of word 1
        {
            int j0 = wic[w0 * 16 + ra];
            int j1 = wic[w0 * 16 + ra + 8];
            short8 g0 = *(const short8*)(chrB + j0 * 128 + sub * 8);
            short8 g1 = *(const short8*)(chrB + j1 * 128 + sub * 8);
            *(short8*)&X[0][(ra + 1) * XS + sub * 8] = g0;
            *(short8*)&X[0][(ra + 9) * XS + sub * 8] = g1;
        }
        int iA0 = wic[(w0 + 1) * 16 + ra];
        int iA1 = wic[(w0 + 1) * 16 + ra + 8];
        __syncthreads();

        float v[4][4];   // per-word max, batched over 4 words
#pragma unroll
        for (int wl = 0; wl < 8; ++wl) {
            const int cur = wl & 1;
            // issue next word's staging loads early (hidden under MFMA)
            short8 g0, g1;
            if (wl < 7) {
                g0 = *(const short8*)(chrB + iA0 * 128 + sub * 8);
                g1 = *(const short8*)(chrB + iA1 * 128 + sub * 8);
            }
            int iB0 = 0, iB1 = 0;
            if (wl < 6) {
                iB0 = wic[(w0 + wl + 2) * 16 + ra];
                iB1 = wic[(w0 + wl + 2) * 16 + ra + 8];
            }

            float4_t acc[4];
#pragma unroll
            for (int p = 0; p < 4; ++p) acc[p] = (float4_t){0.f, 0.f, 0.f, 0.f};
#pragma unroll
            for (int s = 0; s < 12; ++s) {
                short8 a = *(const short8*)&X[cur][(m + (s >> 2)) * XS +
                                                  (s & 3) * 32 + quad * 8];
#pragma unroll
                for (int p = 0; p < 4; ++p)
                    acc[p] = __builtin_amdgcn_mfma_f32_16x16x32_bf16(
                        a, bfrag[s][p], acc[p], 0, 0, 0);
            }

            if (wl < 7) {  // write next buffer (its prev readers are done)
                *(short8*)&X[cur ^ 1][(ra + 1) * XS + sub * 8] = g0;
                *(short8*)&X[cur ^ 1][(ra + 9) * XS + sub * 8] = g1;
                iA0 = iB0; iA1 = iB1;
            }
            __syncthreads();

            // reduce: max over 16 c-rows (4 regs + xor16 + xor32), save
#pragma unroll
            for (int p = 0; p < 4; ++p) {
                float t = fmaxf(fmaxf(acc[p].x, acc[p].y),
                                fmaxf(acc[p].z, acc[p].w));
                t = fmaxf(t, __shfl_xor(t, 16, 64));
                t = fmaxf(t, __shfl_xor(t, 32, 64));
                v[p][wl & 3] = t + bb[p];
            }
            if ((wl & 3) == 3 && quad == 0) {  // batched store of 4 l's
                float* obase = out + OUT_PLANE + b * (ND * NL) + l0 + (wl & 4);
#pragma unroll
                for (int p = 0; p < 4; ++p) {
                    float4_t pk = {v[p][0], v[p][1], v[p][2], v[p][3]};
                    *(float4_t*)&obase[(wave * 64 + p * 16 + m) * NL] = pk;
                }
            }
        }
    } else {
        // ------------------------- word path -------------------------------
        const int b = bid >> 4, l0 = (bid & 15) << 4;
        short8 bfrag[12][4];
#pragma unroll
        for (int s = 0; s < 12; ++s)
#pragma unroll
            for (int p = 0; p < 4; ++p)
                bfrag[s][p] = *(const short8*)(
                    ws + FR_WORD + (((s * 8 + wave * 4 + p) * 64 + lane) << 3));
        float bb[4];
#pragma unroll
        for (int p = 0; p < 4; ++p) bb[p] = biasW[wave * 64 + p * 16 + m];

#pragma unroll
        for (int i0 = 0; i0 < 2; ++i0) {   // 18 rows x 8 segs = 144 jobs
            int i = tid + i0 * 128;
            if (i < 144) {
                int rr = i >> 3, sg = i & 7;
                int l = l0 + rr - 1;
                int idx = (l >= 0 && l < NL) ? wv[b * NL + l] : 0;  // row0=zeros
                const float4_t* src =
                    (const float4_t*)(wordT + idx * 128 + sg * 16);
                float4_t f0 = src[0], f1 = src[1], f2 = src[2], f3 = src[3];
                unsigned short t16[16];
                t16[0]=f2bf(f0.x); t16[1]=f2bf(f0.y); t16[2]=f2bf(f0.z); t16[3]=f2bf(f0.w);
                t16[4]=f2bf(f1.x); t16[5]=f2bf(f1.y); t16[6]=f2bf(f1.z); t16[7]=f2bf(f1.w);
                t16[8]=f2bf(f2.x); t16[9]=f2bf(f2.y); t16[10]=f2bf(f2.z); t16[11]=f2bf(f2.w);
                t16[12]=f2bf(f3.x); t16[13]=f2bf(f3.y); t16[14]=f2bf(f3.z); t16[15]=f2bf(f3.w);
                *(short8*)&X[0][rr * XS + sg * 16]     = *(const short8*)&t16[0];
                *(short8*)&X[0][rr * XS + sg * 16 + 8] = *(const short8*)&t16[8];
            }
        }
        __syncthreads();

        float4_t acc[4];
#pragma unroll
        for (int p = 0; p < 4; ++p) acc[p] = (float4_t){0.f, 0.f, 0.f, 0.f};
#pragma unroll
        for (int s = 0; s < 12; ++s) {
            short8 a = *(const short8*)&X[0][(m + (s >> 2)) * XS +
                                            (s & 3) * 32 + quad * 8];
#pragma unroll
            for (int p = 0; p < 4; ++p)
                acc[p] = __builtin_amdgcn_mfma_f32_16x16x32_bf16(
                    a, bfrag[s][p], acc[p], 0, 0, 0);
        }

        // D[row = l_local = quad*4+reg][col = dout_local = m]; 4 l's per lane
        float* obase = out + b * (ND * NL) + l0 + quad * 4;
#pragma unroll
        for (int p = 0; p < 4; ++p) {
            int dout = wave * 64 + p * 16 + m;
            float4_t pk;
            pk.x = acc[p].x + bb[p];
            pk.y = acc[p].y + bb[p];
            pk.z = acc[p].z + bb[p];
            pk.w = acc[p].w + bb[p];
            *(float4_t*)&obase[dout * NL] = pk;
        }
    }
}

extern "C" void kernel_launch(void* const* d_in, const int* in_sizes, int n_in,
                              void* d_out, int out_size, void* d_ws,
                              size_t ws_size, hipStream_t stream) {
    const int* word_vector   = (const int*)d_in[0];
    const int* words_in_char = (const int*)d_in[1];
    const float* word_table  = (const float*)d_in[2];
    const float* chr_table   = (const float*)d_in[3];
    const float* conv_chr_w  = (const float*)d_in[4];
    const float* conv_chr_b  = (const float*)d_in[5];
    const float* conv_word_w = (const float*)d_in[6];
    const float* conv_word_b = (const float*)d_in[7];
    float* out            = (float*)d_out;
    unsigned short* wsp   = (unsigned short*)d_ws;  // frags + bf16 chr_table

    make_frags<<<448, 256, 0, stream>>>(conv_chr_w, conv_word_w, chr_table, wsp);
    conv_kernel<<<1536, 128, 0, stream>>>(word_vector, words_in_char,
                                          word_table, wsp,
                                          conv_chr_b, conv_word_b, out);
}

// Round 6
// 106.156 us; speedup vs baseline: 1.1099x; 1.0138x over previous
//
#include <hip/hip_runtime.h>

typedef __attribute__((ext_vector_type(8))) short short8;
typedef __attribute__((ext_vector_type(4))) float float4_t;

#define NB 32
#define NL 256
#define ND 128
#define OUT_PLANE (NB * ND * NL)   // elements per stacked output plane
#define XS 136                     // LDS row stride (bf16 units): conflict-free
#define FR_WORD 49152              // word-frag offset in ws (bf16 units)
#define CHRB 98304                 // bf16 chr_table offset in ws (bf16 units)

__device__ inline unsigned short f2bf(float f) {
    union { float f; unsigned int i; } c;
    c.f = f;
    unsigned int r = c.i + 0x7FFFu + ((c.i >> 16) & 1u);  // RN-even
    return (unsigned short)(r >> 16);
}

// ---------------------------------------------------------------------------
// ws prep: [0..49151] char B-frags, [49152..98303] word B-frags,
// [98304..114687] chr_table converted to bf16 (row 0 stays all-zero).
// Frag order: frag[s][nt][lane][j]; B[k'][n]: n=lane&15, k'=s*32+(lane>>4)*8+j,
// tap t=s>>2, k=(s&3)*32+(lane>>4)*8+j.  Value = W[dout][k][t].
// ---------------------------------------------------------------------------
__global__ void make_frags(const float* __restrict__ Wc,
                           const float* __restrict__ Ww,
                           const float* __restrict__ chrT,
                           unsigned short* __restrict__ out) {
    int i = blockIdx.x * 256 + threadIdx.x;            // 0..114687
    if (i < CHRB) {
        const float* W = (i < FR_WORD) ? Wc : Ww;
        int ii = (i < FR_WORD) ? i : i - FR_WORD;
        int j    = ii & 7;
        int lane = (ii >> 3) & 63;
        int nt   = (ii >> 9) & 7;
        int s    = ii >> 12;
        int dout = nt * 16 + (lane & 15);
        int t    = s >> 2;
        int k    = (s & 3) * 32 + ((lane >> 4) & 3) * 8 + j;
        out[i] = f2bf(W[(dout * 128 + k) * 3 + t]);
    } else {
        int j = i - CHRB;                              // 0..16383
        out[i] = f2bf(chrT[j]);
    }
}

// 12-step MFMA accumulation from one staged buffer
__device__ __forceinline__ void mfma12(const unsigned short* __restrict__ buf,
                                       const short8 bfrag[12][4],
                                       int m, int quad, float4_t acc[4]) {
#pragma unroll
    for (int p = 0; p < 4; ++p) acc[p] = (float4_t){0.f, 0.f, 0.f, 0.f};
#pragma unroll
    for (int s = 0; s < 12; ++s) {
        short8 a = *(const short8*)&buf[(m + (s >> 2)) * XS +
                                        (s & 3) * 32 + quad * 8];
#pragma unroll
        for (int p = 0; p < 4; ++p)
            acc[p] = __builtin_amdgcn_mfma_f32_16x16x32_bf16(
                a, bfrag[s][p], acc[p], 0, 0, 0);
    }
}

// ---------------------------------------------------------------------------
// Merged conv kernel. Blocks 0..511: word path (LDS-staged fp32->bf16, 16 l).
// Blocks 512..1535: char path: 8 words/block, 4 rotating LDS buffers,
// 2-word superstep with ONE barrier per superstep; staging loads for words
// j+2/j+3 issued under the MFMA phases of words j/j+1.
// Block = 128 thr = 2 waves; wave w covers douts [w*64, w*64+64).
// ---------------------------------------------------------------------------
__global__ __launch_bounds__(128, 2) void conv_kernel(
    const int* __restrict__ wv, const int* __restrict__ wic,
    const float* __restrict__ wordT,
    const unsigned short* __restrict__ ws,
    const float* __restrict__ biasC, const float* __restrict__ biasW,
    float* __restrict__ out) {
    __shared__ unsigned short X[4][18 * XS];
    const int tid  = threadIdx.x;
    const int wave = tid >> 6, lane = tid & 63;
    const int m = lane & 15, quad = lane >> 4;
    const int bid = blockIdx.x;

    if (bid >= 512) {
        // ------------------------- char path -------------------------------
        const unsigned short* chrB = ws + CHRB;
        const int w0 = (bid - 512) * 8;        // 8 consecutive words, same b
        const int b = w0 >> 8, l0 = w0 & 255;
        short8 bfrag[12][4];
#pragma unroll
        for (int s = 0; s < 12; ++s)
#pragma unroll
            for (int p = 0; p < 4; ++p)
                bfrag[s][p] = *(const short8*)(
                    ws + (((s * 8 + wave * 4 + p) * 64 + lane) << 3));
        float bb[4];
#pragma unroll
        for (int p = 0; p < 4; ++p) bb[p] = biasC[wave * 64 + p * 16 + m];

        // zero pad rows (c=-1 and c=16) in all 4 buffers; never overwritten
        for (int p = tid; p < XS; p += 128)
#pragma unroll
            for (int q = 0; q < 4; ++q) { X[q][p] = 0; X[q][17 * XS + p] = 0; }

        // staging map: 256 jobs = 16 rows x 16 subs of 8 shorts (16 B);
        // thread does rows ra and ra+8 at sub
        const int ra = tid >> 4, sub = tid & 15;

        // prologue: stage words 0,1 into X[0],X[1]
#pragma unroll
        for (int q = 0; q < 2; ++q) {
            int j0 = wic[(w0 + q) * 16 + ra];
            int j1 = wic[(w0 + q) * 16 + ra + 8];
            short8 g0 = *(const short8*)(chrB + j0 * 128 + sub * 8);
            short8 g1 = *(const short8*)(chrB + j1 * 128 + sub * 8);
            *(short8*)&X[q][(ra + 1) * XS + sub * 8] = g0;
            *(short8*)&X[q][(ra + 9) * XS + sub * 8] = g1;
        }
        int iA0 = wic[(w0 + 2) * 16 + ra];       // word 2 idx
        int iA1 = wic[(w0 + 2) * 16 + ra + 8];
        int iC0 = wic[(w0 + 3) * 16 + ra];       // word 3 idx
        int iC1 = wic[(w0 + 3) * 16 + ra + 8];
        __syncthreads();

        float v[4][4];   // per-word max, batched over 4 words
#pragma unroll
        for (int j = 0; j < 8; j += 2) {
            // issue staging loads for word j+2 (hidden under word j's MFMA)
            short8 g0, g1;
            if (j < 6) {
                g0 = *(const short8*)(chrB + iA0 * 128 + sub * 8);
                g1 = *(const short8*)(chrB + iA1 * 128 + sub * 8);
            }

            float4_t acc[4];
            mfma12(X[j & 3], bfrag, m, quad, acc);   // word j

            short8 h0, h1;
            if (j < 6) {
                *(short8*)&X[(j + 2) & 3][(ra + 1) * XS + sub * 8] = g0;
                *(short8*)&X[(j + 2) & 3][(ra + 9) * XS + sub * 8] = g1;
                // issue staging loads for word j+3 (hidden under word j+1)
                h0 = *(const short8*)(chrB + iC0 * 128 + sub * 8);
                h1 = *(const short8*)(chrB + iC1 * 128 + sub * 8);
                if (j < 4) {  // prefetch idx for words j+4, j+5
                    iA0 = wic[(w0 + j + 4) * 16 + ra];
                    iA1 = wic[(w0 + j + 4) * 16 + ra + 8];
                    iC0 = wic[(w0 + j + 5) * 16 + ra];
                    iC1 = wic[(w0 + j + 5) * 16 + ra + 8];
                }
            }

            // epilogue word j: max over 16 c-rows, +bias
#pragma unroll
            for (int p = 0; p < 4; ++p) {
                float t = fmaxf(fmaxf(acc[p].x, acc[p].y),
                                fmaxf(acc[p].z, acc[p].w));
                t = fmaxf(t, __shfl_xor(t, 16, 64));
                t = fmaxf(t, __shfl_xor(t, 32, 64));
                v[p][j & 3] = t + bb[p];
            }

            mfma12(X[(j + 1) & 3], bfrag, m, quad, acc);   // word j+1

            if (j < 6) {
                *(short8*)&X[(j + 3) & 3][(ra + 1) * XS + sub * 8] = h0;
                *(short8*)&X[(j + 3) & 3][(ra + 9) * XS + sub * 8] = h1;
            }

#pragma unroll
            for (int p = 0; p < 4; ++p) {
                float t = fmaxf(fmaxf(acc[p].x, acc[p].y),
                                fmaxf(acc[p].z, acc[p].w));
                t = fmaxf(t, __shfl_xor(t, 16, 64));
                t = fmaxf(t, __shfl_xor(t, 32, 64));
                v[p][(j + 1) & 3] = t + bb[p];
            }
            if (((j + 1) & 3) == 3 && quad == 0) {  // batched store of 4 l's
                float* obase = out + OUT_PLANE + b * (ND * NL) + l0 + (j & 4);
#pragma unroll
                for (int p = 0; p < 4; ++p) {
                    float4_t pk = {v[p][0], v[p][1], v[p][2], v[p][3]};
                    *(float4_t*)&obase[(wave * 64 + p * 16 + m) * NL] = pk;
                }
            }
            __syncthreads();  // protects next superstep's buffer overwrites
        }
    } else {
        // ------------------------- word path -------------------------------
        const int b = bid >> 4, l0 = (bid & 15) << 4;
        short8 bfrag[12][4];
#pragma unroll
        for (int s = 0; s < 12; ++s)
#pragma unroll
            for (int p = 0; p < 4; ++p)
                bfrag[s][p] = *(const short8*)(
                    ws + FR_WORD + (((s * 8 + wave * 4 + p) * 64 + lane) << 3));
        float bb[4];
#pragma unroll
        for (int p = 0; p < 4; ++p) bb[p] = biasW[wave * 64 + p * 16 + m];

#pragma unroll
        for (int i0 = 0; i0 < 2; ++i0) {   // 18 rows x 8 segs = 144 jobs
            int i = tid + i0 * 128;
            if (i < 144) {
                int rr = i >> 3, sg = i & 7;
                int l = l0 + rr - 1;
                int idx = (l >= 0 && l < NL) ? wv[b * NL + l] : 0;  // row0=zeros
                const float4_t* src =
                    (const float4_t*)(wordT + idx * 128 + sg * 16);
                float4_t f0 = src[0], f1 = src[1], f2 = src[2], f3 = src[3];
                unsigned short t16[16];
                t16[0]=f2bf(f0.x); t16[1]=f2bf(f0.y); t16[2]=f2bf(f0.z); t16[3]=f2bf(f0.w);
                t16[4]=f2bf(f1.x); t16[5]=f2bf(f1.y); t16[6]=f2bf(f1.z); t16[7]=f2bf(f1.w);
                t16[8]=f2bf(f2.x); t16[9]=f2bf(f2.y); t16[10]=f2bf(f2.z); t16[11]=f2bf(f2.w);
                t16[12]=f2bf(f3.x); t16[13]=f2bf(f3.y); t16[14]=f2bf(f3.z); t16[15]=f2bf(f3.w);
                *(short8*)&X[0][rr * XS + sg * 16]     = *(const short8*)&t16[0];
                *(short8*)&X[0][rr * XS + sg * 16 + 8] = *(const short8*)&t16[8];
            }
        }
        __syncthreads();

        float4_t acc[4];
#pragma unroll
        for (int p = 0; p < 4; ++p) acc[p] = (float4_t){0.f, 0.f, 0.f, 0.f};
#pragma unroll
        for (int s = 0; s < 12; ++s) {
            short8 a = *(const short8*)&X[0][(m + (s >> 2)) * XS +
                                            (s & 3) * 32 + quad * 8];
#pragma unroll
            for (int p = 0; p < 4; ++p)
                acc[p] = __builtin_amdgcn_mfma_f32_16x16x32_bf16(
                    a, bfrag[s][p], acc[p], 0, 0, 0);
        }

        // D[row = l_local = quad*4+reg][col = dout_local = m]; 4 l's per lane
        float* obase = out + b * (ND * NL) + l0 + quad * 4;
#pragma unroll
        for (int p = 0; p < 4; ++p) {
            int dout = wave * 64 + p * 16 + m;
            float4_t pk;
            pk.x = acc[p].x + bb[p];
            pk.y = acc[p].y + bb[p];
            pk.z = acc[p].z + bb[p];
            pk.w = acc[p].w + bb[p];
            *(float4_t*)&obase[dout * NL] = pk;
        }
    }
}

extern "C" void kernel_launch(void* const* d_in, const int* in_sizes, int n_in,
                              void* d_out, int out_size, void* d_ws,
                              size_t ws_size, hipStream_t stream) {
    const int* word_vector   = (const int*)d_in[0];
    const int* words_in_char = (const int*)d_in[1];
    const float* word_table  = (const float*)d_in[2];
    const float* chr_table   = (const float*)d_in[3];
    const float* conv_chr_w  = (const float*)d_in[4];
    const float* conv_chr_b  = (const float*)d_in[5];
    const float* conv_word_w = (const float*)d_in[6];
    const float* conv_word_b = (const float*)d_in[7];
    float* out            = (float*)d_out;
    unsigned short* wsp   = (unsigned short*)d_ws;  // frags + bf16 chr_table

    make_frags<<<448, 256, 0, stream>>>(conv_chr_w, conv_word_w, chr_table, wsp);
    conv_kernel<<<1536, 128, 0, stream>>>(word_vector, words_in_char,
                                          word_table, wsp,
                                          conv_chr_b, conv_word_b, out);
}